// Round 10
// baseline (522.967 us; speedup 1.0000x reference)
//
#include <hip/hip_runtime.h>
#include <hip/hip_bf16.h>
#include <stdint.h>

typedef unsigned short u16;
typedef __attribute__((ext_vector_type(8))) __bf16 bf16x8;
typedef __attribute__((ext_vector_type(4))) float f32x4;
typedef __attribute__((ext_vector_type(4))) unsigned short u16x4;
typedef __attribute__((ext_vector_type(4))) int i32x4;

#define B_   16
#define N_   512
#define D_   512
#define H_   8
#define DH_  64
#define HID_ 2048
#define M_   8192   // B_*N_
#define FRAG_BH 32768   // per-(b,h) elements of each frag-major buffer

__device__ __forceinline__ u16 f2bf(float f) {
    unsigned u = __float_as_uint(f);
    u += 0x7fffu + ((u >> 16) & 1u);
    return (u16)(u >> 16);
}
__device__ __forceinline__ float bf2f(u16 u) {
    return __uint_as_float(((unsigned)u) << 16);
}
__device__ __forceinline__ f32x4 mfma16(bf16x8 a, bf16x8 b, f32x4 c) {
    return __builtin_amdgcn_mfma_f32_16x16x32_bf16(a, b, c, 0, 0, 0);
}
__device__ __forceinline__ void gload_lds16(const u16* g, u16* l) {
    __builtin_amdgcn_global_load_lds(
        (const __attribute__((address_space(1))) void*)g,
        (__attribute__((address_space(3))) void*)l, 16, 0, 0);
}

// ---------------------------------------------------------------- convert
__device__ __forceinline__ void cvt4(const float* s, u16* d) {
    f32x4 v = *(const f32x4*)s;
    u16x4 o;
    o[0] = f2bf(v[0]); o[1] = f2bf(v[1]); o[2] = f2bf(v[2]); o[3] = f2bf(v[3]);
    *(u16x4*)d = o;
}
__device__ __forceinline__ void cvt4s(const float* s, u16* dh, u16* dl) {
    f32x4 v = *(const f32x4*)s;
    u16x4 oh, ol;
#pragma unroll
    for (int j = 0; j < 4; j++) {
        oh[j] = f2bf(v[j]);
        float r = v[j] - bf2f(oh[j]);
        ol[j] = f2bf(r);
    }
    *(u16x4*)dh = oh;
    *(u16x4*)dl = ol;
}

__global__ __launch_bounds__(256) void convert_all(
    const float* __restrict__ nf, const float* __restrict__ Wq,
    const float* __restrict__ Wk, const float* __restrict__ Wv,
    const float* __restrict__ Wo, const float* __restrict__ W1,
    const float* __restrict__ W2, const float* __restrict__ bq,
    const float* __restrict__ bk, const float* __restrict__ bv,
    u16* __restrict__ xh, u16* __restrict__ xl,
    u16* __restrict__ wqh, u16* __restrict__ wql,
    u16* __restrict__ wob, u16* __restrict__ w1b, u16* __restrict__ w2b,
    float* __restrict__ bqkv)
{
    long i = ((long)blockIdx.x * 256 + threadIdx.x) * 4;
    if (i < 4194304) { cvt4s(nf + i, xh + i, xl + i); return; }
    i -= 4194304;
    if (i < 786432) {
        const float* s = (i < 262144) ? (Wq + i)
                       : (i < 524288) ? (Wk + i - 262144) : (Wv + i - 524288);
        cvt4s(s, wqh + i, wql + i); return;
    }
    i -= 786432;
    if (i < 262144) { cvt4(Wo + i, wob + i); return; }
    i -= 262144;
    if (i < 1048576) { cvt4(W1 + i, w1b + i); return; }
    i -= 1048576;
    if (i < 1048576) { cvt4(W2 + i, w2b + i); return; }
    i -= 1048576;
    if (i < 1536) {
        const float* s = (i < 512) ? (bq + i) : (i < 1024 ? bk + i - 512 : bv + i - 1024);
        *(f32x4*)(bqkv + i) = *(const f32x4*)s;
    }
}

// ---------------------------------------------------------------- bias_prep
// Streams bias [b,q,k,h] (f32, coalesced) + mask, emits bf16 fragment-major
// biasF: idx = ((((bh*32+qt)*8+kt)*4+kf)*64+lane)*4 + r
//        value = bias[b][qt*16+lg*4+r][kt*64+kf*16+lr][h]  (masked -> -3e38)
__global__ __launch_bounds__(512) void bias_prep(
    const float* __restrict__ bias, const int* __restrict__ mask,
    u16* __restrict__ biasF)
{
    __shared__ float Ls[8192];   // [q=16][k=64][h=8]
    __shared__ int Ms[1024];     // [q=16][k=64]
    const int tid = threadIdx.x;
    const int bid = blockIdx.x;
    const int kt = bid & 7, qt = (bid >> 3) & 31, b = bid >> 8;
    const float* src = bias + (((long)b * 512 + qt * 16) * 512 + kt * 64) * 8;
#pragma unroll
    for (int i = 0; i < 4; i++) {
        int lin = i * 2048 + tid * 4;
        int q = lin >> 9, rem = lin & 511;
        *(f32x4*)&Ls[lin] = *(const f32x4*)(src + (long)q * 4096 + rem);
    }
    if (tid < 256) {
        int q = tid >> 4, k4 = (tid & 15) * 4;
        const int* ms = mask + ((long)b * 512 + qt * 16 + q) * 512 + kt * 64 + k4;
        *(i32x4*)&Ms[q * 64 + k4] = *(const i32x4*)ms;
    }
    __syncthreads();
    const int w = tid >> 6, lane = tid & 63;
    const int lr = lane & 15, lg = lane >> 4;
    const long bh = (long)b * 8 + w;
    u16* dst = biasF + (((bh * 32 + qt) * 8 + kt) * 4) * 256 + lane * 4;
#pragma unroll
    for (int kf = 0; kf < 4; kf++) {
        u16x4 o;
#pragma unroll
        for (int r = 0; r < 4; r++) {
            int q = lg * 4 + r, k = kf * 16 + lr;
            float f = Ls[q * 512 + k * 8 + w];
            o[r] = Ms[q * 64 + k] ? f2bf(-3e38f) : f2bf(f);
        }
        *(u16x4*)(dst + kf * 256) = o;
    }
}

#define BM 128
#define BN 128
#define BK 32

// ------------------------------------------------- split-precision QKV GEMM
__global__ __launch_bounds__(256) void gemm_qkv(
    const u16* __restrict__ Ah, const u16* __restrict__ Al,
    const u16* __restrict__ Wh, const u16* __restrict__ Wl,
    const float* __restrict__ bias,
    u16* __restrict__ Qf, u16* __restrict__ Qlf,
    u16* __restrict__ Kf, u16* __restrict__ Klf, u16* __restrict__ Vf)
{
    __shared__ u16 sAh[BM * BK], sAl[BM * BK], sBh[BN * BK], sBl[BN * BK];
    const int Kdim = 512;
    const int tid = threadIdx.x;
    const int w = tid >> 6, lane = tid & 63;
    const int lr = lane & 15, lg = lane >> 4;
    const int nTn = 1536 / BN;
    const int tm = blockIdx.x / nTn, tn = blockIdx.x % nTn;
    const long m0 = (long)tm * BM, n0 = (long)tn * BN;
    const int which = (int)(n0 >> 9);      // 0=Q 1=K 2=V, block-uniform
    const bool vpath = (which == 2);

    f32x4 acc[4][4];
#pragma unroll
    for (int i = 0; i < 4; i++)
#pragma unroll
        for (int j = 0; j < 4; j++) acc[i][j] = (f32x4){0.f, 0.f, 0.f, 0.f};

    const int e0 = w * 512 + lane * 8;
    const int r0 = e0 >> 5, c0 = e0 & 31;
    const int r1 = r0 + 64;
    const long gA0 = (long)r0 * Kdim + c0, gA1 = (long)r1 * Kdim + c0;
    const u16* pAh = Ah + m0 * Kdim;
    const u16* pAl = Al + m0 * Kdim;
    const u16* pBh = Wh + n0 * Kdim;
    const u16* pBl = Wl + n0 * Kdim;
    u16* dAh0 = sAh + w * 512; u16* dAh1 = sAh + w * 512 + 2048;
    u16* dAl0 = sAl + w * 512; u16* dAl1 = sAl + w * 512 + 2048;
    u16* dBh0 = sBh + w * 512; u16* dBh1 = sBh + w * 512 + 2048;
    u16* dBl0 = sBl + w * 512; u16* dBl1 = sBl + w * 512 + 2048;

    const int wr = (w >> 1) * 64, wc = (w & 1) * 64;

    for (int k0 = 0; k0 < Kdim; k0 += BK) {
        gload_lds16(pAh + gA0 + k0, dAh0);
        gload_lds16(pAh + gA1 + k0, dAh1);
        gload_lds16(pBh + gA0 + k0, dBh0);
        gload_lds16(pBh + gA1 + k0, dBh1);
        if (!vpath) {
            gload_lds16(pAl + gA0 + k0, dAl0);
            gload_lds16(pAl + gA1 + k0, dAl1);
            gload_lds16(pBl + gA0 + k0, dBl0);
            gload_lds16(pBl + gA1 + k0, dBl1);
        }
        __syncthreads();
        bf16x8 ah[4], bh[4];
#pragma unroll
        for (int i = 0; i < 4; i++) {
            int ra = (wr + i * 16 + lr) * BK + lg * 8;
            int rb = (wc + i * 16 + lr) * BK + lg * 8;
            ah[i] = *reinterpret_cast<const bf16x8*>(&sAh[ra]);
            bh[i] = *reinterpret_cast<const bf16x8*>(&sBh[rb]);
        }
        if (vpath) {
#pragma unroll
            for (int i = 0; i < 4; i++)
#pragma unroll
                for (int j = 0; j < 4; j++)
                    acc[i][j] = mfma16(ah[i], bh[j], acc[i][j]);
        } else {
            bf16x8 al[4], bl[4];
#pragma unroll
            for (int i = 0; i < 4; i++) {
                int ra = (wr + i * 16 + lr) * BK + lg * 8;
                int rb = (wc + i * 16 + lr) * BK + lg * 8;
                al[i] = *reinterpret_cast<const bf16x8*>(&sAl[ra]);
                bl[i] = *reinterpret_cast<const bf16x8*>(&sBl[rb]);
            }
#pragma unroll
            for (int i = 0; i < 4; i++)
#pragma unroll
                for (int j = 0; j < 4; j++) {
                    acc[i][j] = mfma16(ah[i], bh[j], acc[i][j]);
                    acc[i][j] = mfma16(ah[i], bl[j], acc[i][j]);
                    acc[i][j] = mfma16(al[i], bh[j], acc[i][j]);
                }
        }
        __syncthreads();
    }

#pragma unroll
    for (int i = 0; i < 4; i++) {
#pragma unroll
        for (int j = 0; j < 4; j++) {
#pragma unroll
            for (int r = 0; r < 4; r++) {
                long m = m0 + wr + i * 16 + lg * 4 + r;
                long n = n0 + wc + j * 16 + lr;
                float v = acc[i][j][r] + bias[n];
                int b = (int)(m >> 9), nn = (int)(m & 511);
                int h = ((int)n >> 6) & 7, dh = (int)n & 63;
                long bh_ = (long)b * 8 + h;
                if (which == 2) {
                    int df = dh >> 4, rho = dh & 15;
                    int gam = (nn >> 3) & 3, e = nn & 7, nb32 = nn >> 5;
                    Vf[bh_ * FRAG_BH + (((long)nb32 * 4 + df) * 64 + gam * 16 + rho) * 8 + e]
                        = f2bf(v);
                } else {
                    int nb = nn >> 4, rho = nn & 15;
                    int kk = dh >> 5, gam = (dh >> 3) & 3, e = dh & 7;
                    long idx = bh_ * FRAG_BH + (((long)nb * 2 + kk) * 64 + gam * 16 + rho) * 8 + e;
                    u16 hi = f2bf(v);
                    u16 lo = f2bf(v - bf2f(hi));
                    if (which == 0) { Qf[idx] = hi; Qlf[idx] = lo; }
                    else            { Kf[idx] = hi; Klf[idx] = lo; }
                }
            }
        }
    }
}

// ---------------------------------------------------------------- GEMM (bf16)
template<int EPI>
__global__ __launch_bounds__(256) void gemm_bt(
    const u16* __restrict__ A, const u16* __restrict__ W,
    const float* __restrict__ bias, const float* __restrict__ resid,
    float* __restrict__ outf, u16* __restrict__ outb,
    int Mdim, int Ndim, int Kdim)
{
    __shared__ u16 As[BM * BK];
    __shared__ u16 Bs[BN * BK];
    const int tid = threadIdx.x;
    const int w = tid >> 6, lane = tid & 63;
    const int lr = lane & 15, lg = lane >> 4;
    const int nTn = Ndim / BN;
    const int tm = blockIdx.x / nTn, tn = blockIdx.x % nTn;
    const long m0 = (long)tm * BM, n0 = (long)tn * BN;

    f32x4 acc[4][4];
#pragma unroll
    for (int i = 0; i < 4; i++)
#pragma unroll
        for (int j = 0; j < 4; j++) acc[i][j] = (f32x4){0.f, 0.f, 0.f, 0.f};

    const int e0 = w * 512 + lane * 8;
    const int r0 = e0 >> 5, c0 = e0 & 31;
    const int r1 = r0 + 64, c1 = c0;
    u16* As0 = As + w * 512;
    u16* As1 = As + w * 512 + 2048;
    u16* Bs0 = Bs + w * 512;
    u16* Bs1 = Bs + w * 512 + 2048;
    const u16* Ag = A + m0 * Kdim;
    const u16* Bg = W + n0 * Kdim;

    const int wr = (w >> 1) * 64, wc = (w & 1) * 64;

    for (int k0 = 0; k0 < Kdim; k0 += BK) {
        gload_lds16(Ag + (long)r0 * Kdim + k0 + c0, As0);
        gload_lds16(Ag + (long)r1 * Kdim + k0 + c1, As1);
        gload_lds16(Bg + (long)r0 * Kdim + k0 + c0, Bs0);
        gload_lds16(Bg + (long)r1 * Kdim + k0 + c1, Bs1);
        __syncthreads();
        bf16x8 af[4], bfr[4];
#pragma unroll
        for (int i = 0; i < 4; i++) {
            af[i]  = *reinterpret_cast<const bf16x8*>(&As[(wr + i * 16 + lr) * BK + lg * 8]);
            bfr[i] = *reinterpret_cast<const bf16x8*>(&Bs[(wc + i * 16 + lr) * BK + lg * 8]);
        }
#pragma unroll
        for (int i = 0; i < 4; i++)
#pragma unroll
            for (int j = 0; j < 4; j++)
                acc[i][j] = mfma16(af[i], bfr[j], acc[i][j]);
        __syncthreads();
    }

#pragma unroll
    for (int i = 0; i < 4; i++) {
#pragma unroll
        for (int j = 0; j < 4; j++) {
#pragma unroll
            for (int r = 0; r < 4; r++) {
                long m = m0 + wr + i * 16 + lg * 4 + r;
                long n = n0 + wc + j * 16 + lr;
                float v = acc[i][j][r];
                if (EPI == 1) {
                    long idx = m * Ndim + n;
                    outf[idx] = v + bias[n] + resid[idx];
                } else {
                    float t = v + bias[n];
                    t = t > 0.f ? t : 0.f;
                    outb[m * Ndim + n] = f2bf(t);
                }
            }
        }
    }
}

// ---------------------------------------------------------------- attention
// Barrier-free: 512 blocks = (b, 16-row q-tile); wave w = head w.
// All operands (Q/K/V hi-lo, bias) in fragment-major order -> every global
// load is one coalesced transaction; bias is a per-lane register add.
#define PST  72     // P LDS row stride (u16)

__global__ __launch_bounds__(512) void attn_kernel(
    const u16* __restrict__ Qf, const u16* __restrict__ Qlf,
    const u16* __restrict__ Kf, const u16* __restrict__ Klf,
    const u16* __restrict__ Vf, const u16* __restrict__ biasF,
    u16* __restrict__ ctx)
{
    __shared__ u16 Ps[8 * 16 * PST];    // 18432 B, wave-private regions
    const int tid = threadIdx.x;
    const int w = tid >> 6, lane = tid & 63;
    const int lr = lane & 15, lg = lane >> 4;
    const int b = blockIdx.x >> 5, qt = blockIdx.x & 31;
    const int bq0 = qt * 16;
    const long bh = (long)b * 8 + w;
    const u16* Qfp  = Qf  + bh * FRAG_BH;
    const u16* Qlfp = Qlf + bh * FRAG_BH;
    const u16* Kfp  = Kf  + bh * FRAG_BH;
    const u16* Klfp = Klf + bh * FRAG_BH;
    const u16* Vfp  = Vf  + bh * FRAG_BH;
    const u16* bFp  = biasF + ((bh * 32 + qt) * 8) * 1024 + lane * 4;

    bf16x8 qhf[2], qlf[2];
#pragma unroll
    for (int kk = 0; kk < 2; kk++) {
        long off = (((long)qt * 2 + kk) * 64 + lane) * 8;
        qhf[kk] = *reinterpret_cast<const bf16x8*>(&Qfp[off]);
        qlf[kk] = *reinterpret_cast<const bf16x8*>(&Qlfp[off]);
    }

    f32x4 of[4];
    float m_run[4], l_run[4];
#pragma unroll
    for (int df = 0; df < 4; df++) of[df] = (f32x4){0.f, 0.f, 0.f, 0.f};
#pragma unroll
    for (int r = 0; r < 4; r++) { m_run[r] = -1e30f; l_run[r] = 0.f; }

    u16* Pw = Ps + w * 16 * PST;

#pragma unroll
    for (int kt = 0; kt < 8; kt++) {
        // ---- issue bias + V loads early (consumed after QK^T)
        u16x4 br[4];
#pragma unroll
        for (int kf = 0; kf < 4; kf++)
            br[kf] = *(const u16x4*)(bFp + kt * 1024 + kf * 256);
        bf16x8 vr[2][4];
#pragma unroll
        for (int kk = 0; kk < 2; kk++)
#pragma unroll
            for (int df = 0; df < 4; df++)
                vr[kk][df] = *reinterpret_cast<const bf16x8*>(
                    &Vfp[(((long)(kt * 2 + kk) * 4 + df) * 64 + lane) * 8]);
        // ---- QK^T (frag-major coalesced K loads, hi/lo 3-term)
        f32x4 s[4];
#pragma unroll
        for (int kf = 0; kf < 4; kf++) s[kf] = (f32x4){0.f, 0.f, 0.f, 0.f};
#pragma unroll
        for (int kf = 0; kf < 4; kf++) {
            long kb = (((long)(kt * 4 + kf) * 2) * 64 + lane) * 8;
            bf16x8 kh0 = *reinterpret_cast<const bf16x8*>(&Kfp[kb]);
            bf16x8 kh1 = *reinterpret_cast<const bf16x8*>(&Kfp[kb + 512]);
            bf16x8 kl0 = *reinterpret_cast<const bf16x8*>(&Klfp[kb]);
            bf16x8 kl1 = *reinterpret_cast<const bf16x8*>(&Klfp[kb + 512]);
            __builtin_amdgcn_s_setprio(1);
            s[kf] = mfma16(qhf[0], kh0, s[kf]);
            s[kf] = mfma16(qhf[1], kh1, s[kf]);
            s[kf] = mfma16(qhf[0], kl0, s[kf]);
            s[kf] = mfma16(qhf[1], kl1, s[kf]);
            s[kf] = mfma16(qlf[0], kh0, s[kf]);
            s[kf] = mfma16(qlf[1], kh1, s[kf]);
            __builtin_amdgcn_s_setprio(0);
        }
        // ---- scale + bias (register add), online softmax
#pragma unroll
        for (int kf = 0; kf < 4; kf++)
#pragma unroll
            for (int r = 0; r < 4; r++)
                s[kf][r] = s[kf][r] * 8.0f + bf2f(br[kf][r]);
#pragma unroll
        for (int r = 0; r < 4; r++) {
            float pm = fmaxf(fmaxf(s[0][r], s[1][r]), fmaxf(s[2][r], s[3][r]));
            pm = fmaxf(pm, __shfl_xor(pm, 1));
            pm = fmaxf(pm, __shfl_xor(pm, 2));
            pm = fmaxf(pm, __shfl_xor(pm, 4));
            pm = fmaxf(pm, __shfl_xor(pm, 8));
            float mn_ = fmaxf(m_run[r], pm);
            float fac = __expf(m_run[r] - mn_);
            m_run[r] = mn_;
            float rs = 0.f;
#pragma unroll
            for (int kf = 0; kf < 4; kf++) {
                float p = __expf(s[kf][r] - mn_);
                s[kf][r] = p;
                rs += p;
            }
            rs += __shfl_xor(rs, 1); rs += __shfl_xor(rs, 2);
            rs += __shfl_xor(rs, 4); rs += __shfl_xor(rs, 8);
            l_run[r] = l_run[r] * fac + rs;
#pragma unroll
            for (int df = 0; df < 4; df++) of[df][r] *= fac;
        }
        // ---- P -> LDS (wave-private, no barrier)
#pragma unroll
        for (int kf = 0; kf < 4; kf++)
#pragma unroll
            for (int r = 0; r < 4; r++)
                Pw[(lg * 4 + r) * PST + kf * 16 + lr] = f2bf(s[kf][r]);
        // ---- PV (V already in registers)
#pragma unroll
        for (int kk = 0; kk < 2; kk++) {
            bf16x8 pa = *reinterpret_cast<const bf16x8*>(
                &Pw[lr * PST + kk * 32 + lg * 8]);
            __builtin_amdgcn_s_setprio(1);
#pragma unroll
            for (int df = 0; df < 4; df++)
                of[df] = mfma16(pa, vr[kk][df], of[df]);
            __builtin_amdgcn_s_setprio(0);
        }
    }

    // epilogue: rows bq0 + lg*4 + r
#pragma unroll
    for (int r = 0; r < 4; r++) {
        int q = bq0 + lg * 4 + r;
        float inv = 1.0f / l_run[r];
        u16* crow = ctx + ((long)b * 512 + q) * 512 + w * 64;
#pragma unroll
        for (int df = 0; df < 4; df++)
            crow[df * 16 + lr] = f2bf(of[df][r] * inv);
    }
}

// ---------------------------------------------------------------- layernorm
template<int WB>
__global__ __launch_bounds__(256) void ln_kernel(
    const float* __restrict__ xin, const float* __restrict__ g,
    const float* __restrict__ bta, float* __restrict__ fout, u16* __restrict__ bout)
{
    const int tid = threadIdx.x;
    const int w = tid >> 6, lane = tid & 63;
    const long row = (long)blockIdx.x * 4 + w;
    const float* xp = xin + row * 512 + lane * 8;
    f32x4 v0 = *(const f32x4*)(xp);
    f32x4 v1 = *(const f32x4*)(xp + 4);
    float sum = v0[0] + v0[1] + v0[2] + v0[3] + v1[0] + v1[1] + v1[2] + v1[3];
    float sq = v0[0]*v0[0] + v0[1]*v0[1] + v0[2]*v0[2] + v0[3]*v0[3]
             + v1[0]*v1[0] + v1[1]*v1[1] + v1[2]*v1[2] + v1[3]*v1[3];
#pragma unroll
    for (int m = 1; m <= 32; m <<= 1) {
        sum += __shfl_xor(sum, m);
        sq  += __shfl_xor(sq, m);
    }
    float mu = sum * (1.f / 512.f);
    float var = sq * (1.f / 512.f) - mu * mu;
    float rstd = rsqrtf(var + 1e-5f);
#pragma unroll
    for (int j = 0; j < 8; j++) {
        int c = lane * 8 + j;
        float x = (j < 4) ? v0[j] : v1[j - 4];
        float y = (x - mu) * rstd * g[c] + bta[c];
        fout[row * 512 + c] = y;
        if (WB) bout[row * 512 + c] = f2bf(y);
    }
}

// ---------------------------------------------------------------- launch
extern "C" void kernel_launch(void* const* d_in, const int* in_sizes, int n_in,
                              void* d_out, int out_size, void* d_ws, size_t ws_size,
                              hipStream_t stream)
{
    const float* nfeat     = (const float*)d_in[0];
    const float* attn_bias = (const float*)d_in[1];
    const int*   attn_mask = (const int*)d_in[2];
    const float* Wq = (const float*)d_in[3];
    const float* bq = (const float*)d_in[4];
    const float* Wk = (const float*)d_in[5];
    const float* bk = (const float*)d_in[6];
    const float* Wv = (const float*)d_in[7];
    const float* bv = (const float*)d_in[8];
    const float* Wo = (const float*)d_in[9];
    const float* bo = (const float*)d_in[10];
    const float* W1 = (const float*)d_in[11];
    const float* b1 = (const float*)d_in[12];
    const float* W2 = (const float*)d_in[13];
    const float* b2 = (const float*)d_in[14];
    const float* ln1_g = (const float*)d_in[15];
    const float* ln1_b = (const float*)d_in[16];
    const float* ln2_g = (const float*)d_in[17];
    const float* ln2_b = (const float*)d_in[18];

    char* ws = (char*)d_ws;
    size_t off = 0;
    auto alloc = [&](size_t bytes) -> void* {
        void* p = ws + off;
        off += (bytes + 255) & ~(size_t)255;
        return p;
    };
    u16* xh    = (u16*)alloc((size_t)M_ * D_ * 2);
    u16* xl    = (u16*)alloc((size_t)M_ * D_ * 2);
    u16* wqh   = (u16*)alloc((size_t)1536 * 512 * 2);
    u16* wql   = (u16*)alloc((size_t)1536 * 512 * 2);
    u16* wob   = (u16*)alloc((size_t)512 * 512 * 2);
    u16* w1b   = (u16*)alloc((size_t)2048 * 512 * 2);
    u16* w2b   = (u16*)alloc((size_t)512 * 2048 * 2);
    float* bqkv = (float*)alloc(1536 * 4);
    u16* Qf    = (u16*)alloc((size_t)128 * FRAG_BH * 2);
    u16* Qlf   = (u16*)alloc((size_t)128 * FRAG_BH * 2);
    u16* Kf    = (u16*)alloc((size_t)128 * FRAG_BH * 2);
    u16* Klf   = (u16*)alloc((size_t)128 * FRAG_BH * 2);
    u16* Vf    = (u16*)alloc((size_t)128 * FRAG_BH * 2);
    u16* biasF = (u16*)alloc((size_t)128 * 32 * 8 * 4 * 64 * 4 * 2);  // 67 MB
    u16* ctx   = (u16*)alloc((size_t)M_ * D_ * 2);
    float* xres = (float*)alloc((size_t)M_ * D_ * 4);
    float* x1f  = (float*)alloc((size_t)M_ * D_ * 4);
    u16* x1b   = (u16*)alloc((size_t)M_ * D_ * 2);
    u16* hb    = (u16*)alloc((size_t)M_ * HID_ * 2);

    convert_all<<<7170, 256, 0, stream>>>(nfeat, Wq, Wk, Wv, Wo, W1, W2, bq, bk, bv,
                                          xh, xl, wqh, wql, wob, w1b, w2b, bqkv);
    bias_prep<<<16 * 32 * 8, 512, 0, stream>>>(attn_bias, attn_mask, biasF);
    gemm_qkv<<<(M_/BM) * (1536/BN), 256, 0, stream>>>(
        xh, xl, wqh, wql, bqkv, Qf, Qlf, Kf, Klf, Vf);
    attn_kernel<<<B_ * 32, 512, 0, stream>>>(
        Qf, Qlf, Kf, Klf, Vf, biasF, ctx);
    gemm_bt<1><<<(M_/BM) * (512/BN), 256, 0, stream>>>(
        ctx, wob, bo, nfeat, xres, nullptr, M_, 512, 512);
    ln_kernel<1><<<M_ / 4, 256, 0, stream>>>(xres, ln1_g, ln1_b, x1f, x1b);
    gemm_bt<2><<<(M_/BM) * (HID_/BN), 256, 0, stream>>>(
        x1b, w1b, b1, nullptr, nullptr, hb, M_, HID_, 512);
    gemm_bt<1><<<(M_/BM) * (512/BN), 256, 0, stream>>>(
        hb, w2b, b2, x1f, xres, nullptr, M_, 512, 2048);
    ln_kernel<0><<<M_ / 4, 256, 0, stream>>>(xres, ln2_g, ln2_b, (float*)d_out, nullptr);
}